// Round 1
// baseline (401.832 us; speedup 1.0000x reference)
//
#include <hip/hip_runtime.h>
#include <math.h>

typedef unsigned short u16;
typedef __attribute__((ext_vector_type(4))) float f32x4;
typedef __attribute__((ext_vector_type(8))) short bf16x8;

#define B_ 2
#define S_ 2048
#define DM 1024
#define H_ 16
#define AD 64
#define ME 4194304  // elems in one 4096x1024 matrix

__device__ inline u16 f2bf(float f) {
  union { float f; unsigned u; } v; v.f = f;
  unsigned r = v.u + 0x7fffu + ((v.u >> 16) & 1u);
  return (u16)(r >> 16);
}

// ---------------- states f32 -> bf16 ----------------
__global__ __launch_bounds__(256) void conv_states(const float* __restrict__ in,
                                                   u16* __restrict__ out) {
  int i = (blockIdx.x * 256 + threadIdx.x) * 8;
  const float4* p = (const float4*)(in + i);
  float4 a = p[0], b = p[1];
  bf16x8 o;
  o[0] = (short)f2bf(a.x); o[1] = (short)f2bf(a.y);
  o[2] = (short)f2bf(a.z); o[3] = (short)f2bf(a.w);
  o[4] = (short)f2bf(b.x); o[5] = (short)f2bf(b.y);
  o[6] = (short)f2bf(b.z); o[7] = (short)f2bf(b.w);
  *(bf16x8*)&out[i] = o;
}

// ---------------- W [K][N] f32 -> Wt [N][K] bf16 (4 weights) ----------------
__global__ void transpose_w(const float* __restrict__ Wq, const float* __restrict__ Wk,
                            const float* __restrict__ Wv, const float* __restrict__ Wo,
                            u16* __restrict__ Wt) {
  __shared__ float t[32][33];
  int z = blockIdx.z;
  const float* W = (z == 0) ? Wq : (z == 1) ? Wk : (z == 2) ? Wv : Wo;
  u16* out = Wt + (size_t)z * DM * DM;
  int n0 = blockIdx.x * 32, k0 = blockIdx.y * 32;
  int tx = threadIdx.x, ty = threadIdx.y;
  t[ty][tx] = W[(k0 + ty) * DM + n0 + tx];
  __syncthreads();
  out[(n0 + ty) * DM + k0 + tx] = f2bf(t[tx][ty]);
}

// ---------------- fused QKV projection GEMM + tanh ----------------
// C[m][n] = tanh(sum_k A[m][k]*Wt[n][k] + bias[n]); z selects q/k/v.
// Q,K written [B][H][S][D]; V written transposed [B][H][D][S].
__global__ __launch_bounds__(256) void qkv_gemm(
    const u16* __restrict__ A, const u16* __restrict__ Wt,
    const float* __restrict__ bq, const float* __restrict__ bk, const float* __restrict__ bv,
    u16* __restrict__ Qw, u16* __restrict__ Kw, u16* __restrict__ Vtw) {
  __shared__ __attribute__((aligned(16))) u16 lA[128 * 32];
  __shared__ __attribute__((aligned(16))) u16 lB[128 * 32];
  const int z = blockIdx.z;
  const u16* Bt = Wt + (size_t)z * DM * DM;
  const int m0 = blockIdx.y * 128, n0 = blockIdx.x * 128;
  const int tid = threadIdx.x;
  const int wid = tid >> 6, l = tid & 63;
  const int lr = l & 15, lk = l >> 4;
  const int wm = (wid >> 1) * 64, wn = (wid & 1) * 64;

  f32x4 acc[4][4] = {};

  for (int k0 = 0; k0 < DM; k0 += 32) {
#pragma unroll
    for (int it = 0; it < 2; ++it) {
      int idx = tid + it * 256;
      int row = idx >> 2;
      int c8 = (idx & 3) * 8;
      *(bf16x8*)&lA[row * 32 + c8] = *(const bf16x8*)&A[(m0 + row) * DM + k0 + c8];
      *(bf16x8*)&lB[row * 32 + c8] = *(const bf16x8*)&Bt[(n0 + row) * DM + k0 + c8];
    }
    __syncthreads();
    bf16x8 af[4], bfr[4];
#pragma unroll
    for (int g = 0; g < 4; ++g) {
      af[g]  = *(const bf16x8*)&lA[(wm + g * 16 + lr) * 32 + lk * 8];
      bfr[g] = *(const bf16x8*)&lB[(wn + g * 16 + lr) * 32 + lk * 8];
    }
#pragma unroll
    for (int mg = 0; mg < 4; ++mg)
#pragma unroll
      for (int ng = 0; ng < 4; ++ng)
        acc[mg][ng] = __builtin_amdgcn_mfma_f32_16x16x32_bf16(af[mg], bfr[ng], acc[mg][ng], 0, 0, 0);
    __syncthreads();
  }

  const float* bias = (z == 0) ? bq : (z == 1) ? bk : bv;
#pragma unroll
  for (int mg = 0; mg < 4; ++mg)
#pragma unroll
    for (int ng = 0; ng < 4; ++ng)
#pragma unroll
      for (int r = 0; r < 4; ++r) {
        int m = m0 + wm + mg * 16 + lk * 4 + r;
        int n = n0 + wn + ng * 16 + lr;
        float v = tanhf(acc[mg][ng][r] + bias[n]);
        u16 h16 = f2bf(v);
        int bb = m >> 11, s = m & 2047, hh = n >> 6, d = n & 63;
        if (z == 2) Vtw[((size_t)(bb * H_ + hh) * AD + d) * S_ + s] = h16;
        else ((z == 0) ? Qw : Kw)[((size_t)(bb * H_ + hh) * S_ + s) * AD + d] = h16;
      }
}

// ---------------- output projection GEMM + tanh (f32 out) ----------------
__global__ __launch_bounds__(256) void out_gemm(
    const u16* __restrict__ A, const u16* __restrict__ Bt,
    const float* __restrict__ bo, float* __restrict__ out) {
  __shared__ __attribute__((aligned(16))) u16 lA[128 * 32];
  __shared__ __attribute__((aligned(16))) u16 lB[128 * 32];
  const int m0 = blockIdx.y * 128, n0 = blockIdx.x * 128;
  const int tid = threadIdx.x;
  const int wid = tid >> 6, l = tid & 63;
  const int lr = l & 15, lk = l >> 4;
  const int wm = (wid >> 1) * 64, wn = (wid & 1) * 64;

  f32x4 acc[4][4] = {};

  for (int k0 = 0; k0 < DM; k0 += 32) {
#pragma unroll
    for (int it = 0; it < 2; ++it) {
      int idx = tid + it * 256;
      int row = idx >> 2;
      int c8 = (idx & 3) * 8;
      *(bf16x8*)&lA[row * 32 + c8] = *(const bf16x8*)&A[(m0 + row) * DM + k0 + c8];
      *(bf16x8*)&lB[row * 32 + c8] = *(const bf16x8*)&Bt[(n0 + row) * DM + k0 + c8];
    }
    __syncthreads();
    bf16x8 af[4], bfr[4];
#pragma unroll
    for (int g = 0; g < 4; ++g) {
      af[g]  = *(const bf16x8*)&lA[(wm + g * 16 + lr) * 32 + lk * 8];
      bfr[g] = *(const bf16x8*)&lB[(wn + g * 16 + lr) * 32 + lk * 8];
    }
#pragma unroll
    for (int mg = 0; mg < 4; ++mg)
#pragma unroll
      for (int ng = 0; ng < 4; ++ng)
        acc[mg][ng] = __builtin_amdgcn_mfma_f32_16x16x32_bf16(af[mg], bfr[ng], acc[mg][ng], 0, 0, 0);
    __syncthreads();
  }

#pragma unroll
  for (int mg = 0; mg < 4; ++mg)
#pragma unroll
    for (int ng = 0; ng < 4; ++ng)
#pragma unroll
      for (int r = 0; r < 4; ++r) {
        int m = m0 + wm + mg * 16 + lk * 4 + r;
        int n = n0 + wn + ng * 16 + lr;
        out[(size_t)m * DM + n] = tanhf(acc[mg][ng][r] + bo[n]);
      }
}

// ---------------- causal flash attention ----------------
// Q,K: [B][H][S][D] bf16; Vt: [B][H][D][S] bf16; ctx out: [B][S][H*D] bf16.
// One workgroup per (q-tile of 64, b*h); 4 waves, each owns 16 q-rows.
__global__ __launch_bounds__(256) void attn_kernel(
    const u16* __restrict__ Q, const u16* __restrict__ K,
    const u16* __restrict__ Vt, u16* __restrict__ ctx) {
  __shared__ __attribute__((aligned(16))) u16 pbuf[4][16 * 64];
  const int qt = blockIdx.x, bh = blockIdx.y;
  const int b = bh >> 4, h = bh & 15;
  const int tid = threadIdx.x, wid = tid >> 6, l = tid & 63;
  const int lr = l & 15, lk = l >> 4;
  const u16* Qb = Q + (size_t)bh * S_ * AD;
  const u16* Kb = K + (size_t)bh * S_ * AD;
  const u16* Vb = Vt + (size_t)bh * AD * S_;
  u16* myp = &pbuf[wid][0];

  const int q0 = qt * 64 + wid * 16;

  bf16x8 qf[2];
#pragma unroll
  for (int kg = 0; kg < 2; ++kg)
    qf[kg] = *(const bf16x8*)&Qb[(q0 + lr) * AD + kg * 32 + lk * 8];

  f32x4 acc[4] = {};
  float mrun[4], lrun[4];
#pragma unroll
  for (int r = 0; r < 4; ++r) { mrun[r] = -1e30f; lrun[r] = 0.f; }

  const int nkb = qt + 1;
  for (int kb = 0; kb < nkb; ++kb) {
    const int kv0 = kb * 64;
    f32x4 sc[4] = {};
#pragma unroll
    for (int ng = 0; ng < 4; ++ng)
#pragma unroll
      for (int kg = 0; kg < 2; ++kg) {
        bf16x8 kf = *(const bf16x8*)&Kb[(kv0 + ng * 16 + lr) * AD + kg * 32 + lk * 8];
        sc[ng] = __builtin_amdgcn_mfma_f32_16x16x32_bf16(qf[kg], kf, sc[ng], 0, 0, 0);
      }
    // scale + causal mask + local row max
    float lm[4];
#pragma unroll
    for (int r = 0; r < 4; ++r) {
      const int qrow = q0 + lk * 4 + r;
      float best = -1e30f;
#pragma unroll
      for (int ng = 0; ng < 4; ++ng) {
        const int kvi = kv0 + ng * 16 + lr;
        float s = sc[ng][r] * 0.125f;
        if (kvi > qrow) s = -1e30f;
        sc[ng][r] = s;
        best = fmaxf(best, s);
      }
      lm[r] = best;
    }
#pragma unroll
    for (int off = 8; off >= 1; off >>= 1)
#pragma unroll
      for (int r = 0; r < 4; ++r)
        lm[r] = fmaxf(lm[r], __shfl_xor(lm[r], off));
    float fs[4], rs[4];
#pragma unroll
    for (int r = 0; r < 4; ++r) {
      float mn = fmaxf(mrun[r], lm[r]);
      fs[r] = __expf(mrun[r] - mn);
      mrun[r] = mn;
      rs[r] = 0.f;
    }
#pragma unroll
    for (int ng = 0; ng < 4; ++ng)
#pragma unroll
      for (int r = 0; r < 4; ++r) {
        float p = __expf(sc[ng][r] - mrun[r]);
        sc[ng][r] = p;
        rs[r] += p;
      }
#pragma unroll
    for (int off = 8; off >= 1; off >>= 1)
#pragma unroll
      for (int r = 0; r < 4; ++r)
        rs[r] += __shfl_xor(rs[r], off);
#pragma unroll
    for (int r = 0; r < 4; ++r) lrun[r] = lrun[r] * fs[r] + rs[r];
#pragma unroll
    for (int g = 0; g < 4; ++g)
#pragma unroll
      for (int r = 0; r < 4; ++r)
        acc[g][r] *= fs[r];
    // P -> LDS (bf16), per-wave buffer
#pragma unroll
    for (int ng = 0; ng < 4; ++ng)
#pragma unroll
      for (int r = 0; r < 4; ++r)
        myp[(lk * 4 + r) * 64 + ng * 16 + lr] = f2bf(sc[ng][r]);
    __syncthreads();
    bf16x8 pf[2];
#pragma unroll
    for (int kg = 0; kg < 2; ++kg)
      pf[kg] = *(const bf16x8*)&myp[lr * 64 + kg * 32 + lk * 8];
#pragma unroll
    for (int g = 0; g < 4; ++g)
#pragma unroll
      for (int kg = 0; kg < 2; ++kg) {
        bf16x8 vf = *(const bf16x8*)&Vb[(g * 16 + lr) * S_ + kv0 + kg * 32 + lk * 8];
        acc[g] = __builtin_amdgcn_mfma_f32_16x16x32_bf16(pf[kg], vf, acc[g], 0, 0, 0);
      }
    __syncthreads();
  }
#pragma unroll
  for (int g = 0; g < 4; ++g)
#pragma unroll
    for (int r = 0; r < 4; ++r) {
      int q = q0 + lk * 4 + r;
      int d = g * 16 + lr;
      ctx[((size_t)b * S_ + q) * DM + h * AD + d] = f2bf(acc[g][r] / lrun[r]);
    }
}

extern "C" void kernel_launch(void* const* d_in, const int* in_sizes, int n_in,
                              void* d_out, int out_size, void* d_ws, size_t ws_size,
                              hipStream_t stream) {
  const float* states = (const float*)d_in[0];
  const float* Wq = (const float*)d_in[1];
  const float* bq = (const float*)d_in[2];
  const float* Wk = (const float*)d_in[3];
  const float* bk = (const float*)d_in[4];
  const float* Wv = (const float*)d_in[5];
  const float* bv = (const float*)d_in[6];
  const float* Wo = (const float*)d_in[7];
  const float* bo = (const float*)d_in[8];
  float* out = (float*)d_out;

  // workspace layout (bf16 elems): states | Wt[4] | Q | K | Vt | ctx  = 48 MB
  u16* sbf = (u16*)d_ws;
  u16* wt  = sbf + ME;
  u16* Qw  = wt + ME;
  u16* Kw  = Qw + ME;
  u16* Vtw = Kw + ME;
  u16* ctx = Vtw + ME;

  conv_states<<<ME / (256 * 8), 256, 0, stream>>>(states, sbf);
  transpose_w<<<dim3(32, 32, 4), dim3(32, 32), 0, stream>>>(Wq, Wk, Wv, Wo, wt);
  qkv_gemm<<<dim3(8, 32, 3), 256, 0, stream>>>(sbf, wt, bq, bk, bv, Qw, Kw, Vtw);
  attn_kernel<<<dim3(32, 32), 256, 0, stream>>>(Qw, Kw, Vtw, ctx);
  out_gemm<<<dim3(8, 32), 256, 0, stream>>>(ctx, wt + 3 * (size_t)DM * DM, bo, out);
}

// Round 2
// 338.024 us; speedup vs baseline: 1.1888x; 1.1888x over previous
//
#include <hip/hip_runtime.h>
#include <math.h>

typedef unsigned short u16;
typedef __attribute__((ext_vector_type(4))) float f32x4;
typedef __attribute__((ext_vector_type(8))) short bf16x8;

#define B_ 2
#define S_ 2048
#define DM 1024
#define H_ 16
#define AD 64
#define ME 4194304  // elems in one 4096x1024 matrix

#define GLL(g, s) __builtin_amdgcn_global_load_lds( \
  (const __attribute__((address_space(1))) void*)(g), \
  (__attribute__((address_space(3))) void*)(s), 16, 0, 0)

__device__ inline u16 f2bf(float f) {
  union { float f; unsigned u; } v; v.f = f;
  unsigned r = v.u + 0x7fffu + ((v.u >> 16) & 1u);
  return (u16)(r >> 16);
}

// ---------------- states f32 -> bf16 ----------------
__global__ __launch_bounds__(256) void conv_states(const float* __restrict__ in,
                                                   u16* __restrict__ out) {
  int i = (blockIdx.x * 256 + threadIdx.x) * 8;
  const float4* p = (const float4*)(in + i);
  float4 a = p[0], b = p[1];
  bf16x8 o;
  o[0] = (short)f2bf(a.x); o[1] = (short)f2bf(a.y);
  o[2] = (short)f2bf(a.z); o[3] = (short)f2bf(a.w);
  o[4] = (short)f2bf(b.x); o[5] = (short)f2bf(b.y);
  o[6] = (short)f2bf(b.z); o[7] = (short)f2bf(b.w);
  *(bf16x8*)&out[i] = o;
}

// ---------------- W [K][N] f32 -> Wt [N][K] bf16 (4 weights) ----------------
__global__ void transpose_w(const float* __restrict__ Wq, const float* __restrict__ Wk,
                            const float* __restrict__ Wv, const float* __restrict__ Wo,
                            u16* __restrict__ Wt) {
  __shared__ float t[32][33];
  int z = blockIdx.z;
  const float* W = (z == 0) ? Wq : (z == 1) ? Wk : (z == 2) ? Wv : Wo;
  u16* out = Wt + (size_t)z * DM * DM;
  int n0 = blockIdx.x * 32, k0 = blockIdx.y * 32;
  int tx = threadIdx.x, ty = threadIdx.y;
  t[ty][tx] = W[(k0 + ty) * DM + n0 + tx];
  __syncthreads();
  out[(n0 + ty) * DM + k0 + tx] = f2bf(t[tx][ty]);
}

// ---------------- fused QKV projection GEMM + tanh ----------------
__global__ __launch_bounds__(256) void qkv_gemm(
    const u16* __restrict__ A, const u16* __restrict__ Wt,
    const float* __restrict__ bq, const float* __restrict__ bk, const float* __restrict__ bv,
    u16* __restrict__ Qw, u16* __restrict__ Kw, u16* __restrict__ Vtw) {
  __shared__ __attribute__((aligned(16))) u16 lA[128 * 32];
  __shared__ __attribute__((aligned(16))) u16 lB[128 * 32];
  const int z = blockIdx.z;
  const u16* Bt = Wt + (size_t)z * DM * DM;
  const int m0 = blockIdx.y * 128, n0 = blockIdx.x * 128;
  const int tid = threadIdx.x;
  const int wid = tid >> 6, l = tid & 63;
  const int lr = l & 15, lk = l >> 4;
  const int wm = (wid >> 1) * 64, wn = (wid & 1) * 64;
  const int srow = wid * 32 + (l >> 2);   // staging row (instr 0)
  const int scol = (l & 3) * 8;           // staging col elem

  f32x4 acc[4][4] = {};

  for (int k0 = 0; k0 < DM; k0 += 32) {
    const u16* gA = &A[(size_t)(m0 + srow) * DM + k0 + scol];
    const u16* gB = &Bt[(size_t)(n0 + srow) * DM + k0 + scol];
    GLL(gA,           lA + wid * 1024);
    GLL(gA + 16 * DM, lA + wid * 1024 + 512);
    GLL(gB,           lB + wid * 1024);
    GLL(gB + 16 * DM, lB + wid * 1024 + 512);
    __syncthreads();
    bf16x8 af[4], bfr[4];
#pragma unroll
    for (int g = 0; g < 4; ++g) {
      af[g]  = *(const bf16x8*)&lA[(wm + g * 16 + lr) * 32 + lk * 8];
      bfr[g] = *(const bf16x8*)&lB[(wn + g * 16 + lr) * 32 + lk * 8];
    }
#pragma unroll
    for (int mg = 0; mg < 4; ++mg)
#pragma unroll
      for (int ng = 0; ng < 4; ++ng)
        acc[mg][ng] = __builtin_amdgcn_mfma_f32_16x16x32_bf16(af[mg], bfr[ng], acc[mg][ng], 0, 0, 0);
    __syncthreads();
  }

  const float* bias = (z == 0) ? bq : (z == 1) ? bk : bv;
#pragma unroll
  for (int mg = 0; mg < 4; ++mg)
#pragma unroll
    for (int ng = 0; ng < 4; ++ng)
#pragma unroll
      for (int r = 0; r < 4; ++r) {
        int m = m0 + wm + mg * 16 + lk * 4 + r;
        int n = n0 + wn + ng * 16 + lr;
        float v = tanhf(acc[mg][ng][r] + bias[n]);
        u16 h16 = f2bf(v);
        int bb = m >> 11, s = m & 2047, hh = n >> 6, d = n & 63;
        if (z == 2) Vtw[((size_t)(bb * H_ + hh) * AD + d) * S_ + s] = h16;
        else ((z == 0) ? Qw : Kw)[((size_t)(bb * H_ + hh) * S_ + s) * AD + d] = h16;
      }
}

// ---------------- output projection GEMM + tanh (f32 out) ----------------
__global__ __launch_bounds__(256) void out_gemm(
    const u16* __restrict__ A, const u16* __restrict__ Bt,
    const float* __restrict__ bo, float* __restrict__ out) {
  __shared__ __attribute__((aligned(16))) u16 lA[128 * 32];
  __shared__ __attribute__((aligned(16))) u16 lB[128 * 32];
  const int m0 = blockIdx.y * 128, n0 = blockIdx.x * 128;
  const int tid = threadIdx.x;
  const int wid = tid >> 6, l = tid & 63;
  const int lr = l & 15, lk = l >> 4;
  const int wm = (wid >> 1) * 64, wn = (wid & 1) * 64;
  const int srow = wid * 32 + (l >> 2);
  const int scol = (l & 3) * 8;

  f32x4 acc[4][4] = {};

  for (int k0 = 0; k0 < DM; k0 += 32) {
    const u16* gA = &A[(size_t)(m0 + srow) * DM + k0 + scol];
    const u16* gB = &Bt[(size_t)(n0 + srow) * DM + k0 + scol];
    GLL(gA,           lA + wid * 1024);
    GLL(gA + 16 * DM, lA + wid * 1024 + 512);
    GLL(gB,           lB + wid * 1024);
    GLL(gB + 16 * DM, lB + wid * 1024 + 512);
    __syncthreads();
    bf16x8 af[4], bfr[4];
#pragma unroll
    for (int g = 0; g < 4; ++g) {
      af[g]  = *(const bf16x8*)&lA[(wm + g * 16 + lr) * 32 + lk * 8];
      bfr[g] = *(const bf16x8*)&lB[(wn + g * 16 + lr) * 32 + lk * 8];
    }
#pragma unroll
    for (int mg = 0; mg < 4; ++mg)
#pragma unroll
      for (int ng = 0; ng < 4; ++ng)
        acc[mg][ng] = __builtin_amdgcn_mfma_f32_16x16x32_bf16(af[mg], bfr[ng], acc[mg][ng], 0, 0, 0);
    __syncthreads();
  }

#pragma unroll
  for (int mg = 0; mg < 4; ++mg)
#pragma unroll
    for (int ng = 0; ng < 4; ++ng)
#pragma unroll
      for (int r = 0; r < 4; ++r) {
        int m = m0 + wm + mg * 16 + lk * 4 + r;
        int n = n0 + wn + ng * 16 + lr;
        out[(size_t)m * DM + n] = tanhf(acc[mg][ng][r] + bo[n]);
      }
}

// ---------------- causal flash attention ----------------
// Q,K: [B][H][S][D] bf16; Vt: [B][H][D][S] bf16; ctx out: [B][S][H*D] bf16.
// 4 independent waves/block, each owns 16 q-rows. No barriers (per-wave P buf).
#define PST 72  // P LDS row stride (u16): 144B, 16B-aligned, breaks bank conflict

__device__ inline void load_k8(bf16x8* dst, const u16* Kb, int base, int lr, int lk) {
#pragma unroll
  for (int ng = 0; ng < 4; ++ng)
#pragma unroll
    for (int kg = 0; kg < 2; ++kg)
      dst[ng * 2 + kg] = *(const bf16x8*)&Kb[(size_t)(base + ng * 16 + lr) * AD + kg * 32 + lk * 8];
}

__global__ __launch_bounds__(256) void attn_kernel(
    const u16* __restrict__ Q, const u16* __restrict__ K,
    const u16* __restrict__ Vt, u16* __restrict__ ctx) {
  __shared__ __attribute__((aligned(16))) u16 pbuf[4][16 * PST];
  const int qt = 31 - blockIdx.x;          // longest blocks dispatch first
  const int bh = blockIdx.y;
  const int b = bh >> 4, h = bh & 15;
  const int tid = threadIdx.x, wid = tid >> 6, l = tid & 63;
  const int lr = l & 15, lk = l >> 4;
  const u16* Qb = Q + (size_t)bh * S_ * AD;
  const u16* Kb = K + (size_t)bh * S_ * AD;
  const u16* Vb = Vt + (size_t)bh * AD * S_;
  u16* myp = &pbuf[wid][0];

  const int q0 = qt * 64 + wid * 16;

  bf16x8 qf[2];
#pragma unroll
  for (int kg = 0; kg < 2; ++kg)
    qf[kg] = *(const bf16x8*)&Qb[(size_t)(q0 + lr) * AD + kg * 32 + lk * 8];

  f32x4 acc[4] = {};
  float mrun[4], lrun[4];
#pragma unroll
  for (int r = 0; r < 4; ++r) { mrun[r] = -1e30f; lrun[r] = 0.f; }

  const int nkb = qt + 1;
  bf16x8 kf[8];
  load_k8(kf, Kb, 0, lr, lk);

  for (int kb = 0; kb < nkb; ++kb) {
    const int kv0 = kb * 64;
    // issue V loads for this block early; softmax hides their latency
    bf16x8 vf[8];
#pragma unroll
    for (int g = 0; g < 4; ++g)
#pragma unroll
      for (int kg = 0; kg < 2; ++kg)
        vf[g * 2 + kg] = *(const bf16x8*)&Vb[(size_t)(g * 16 + lr) * S_ + kv0 + kg * 32 + lk * 8];

    // QK^T
    f32x4 sc[4] = {};
#pragma unroll
    for (int ng = 0; ng < 4; ++ng)
#pragma unroll
      for (int kg = 0; kg < 2; ++kg)
        sc[ng] = __builtin_amdgcn_mfma_f32_16x16x32_bf16(qf[kg], kf[ng * 2 + kg], sc[ng], 0, 0, 0);

    // overwrite kf with next block's K (kf dead after QK); rest of iter hides latency
    const int kvn = (kb + 1 < nkb) ? kv0 + 64 : kv0;
    load_k8(kf, Kb, kvn, lr, lk);

    // scale + causal mask + local row max
    float lm[4];
#pragma unroll
    for (int r = 0; r < 4; ++r) {
      const int qrow = q0 + lk * 4 + r;
      float best = -1e30f;
#pragma unroll
      for (int ng = 0; ng < 4; ++ng) {
        const int kvi = kv0 + ng * 16 + lr;
        float s = sc[ng][r] * 0.125f;
        if (kvi > qrow) s = -1e30f;
        sc[ng][r] = s;
        best = fmaxf(best, s);
      }
      lm[r] = best;
    }
#pragma unroll
    for (int off = 8; off >= 1; off >>= 1)
#pragma unroll
      for (int r = 0; r < 4; ++r)
        lm[r] = fmaxf(lm[r], __shfl_xor(lm[r], off));
    float fs[4], rs[4];
#pragma unroll
    for (int r = 0; r < 4; ++r) {
      float mn = fmaxf(mrun[r], lm[r]);
      fs[r] = __expf(mrun[r] - mn);
      mrun[r] = mn;
      rs[r] = 0.f;
    }
#pragma unroll
    for (int ng = 0; ng < 4; ++ng)
#pragma unroll
      for (int r = 0; r < 4; ++r) {
        float p = __expf(sc[ng][r] - mrun[r]);
        sc[ng][r] = p;
        rs[r] += p;
      }
#pragma unroll
    for (int off = 8; off >= 1; off >>= 1)
#pragma unroll
      for (int r = 0; r < 4; ++r)
        rs[r] += __shfl_xor(rs[r], off);
#pragma unroll
    for (int r = 0; r < 4; ++r) lrun[r] = lrun[r] * fs[r] + rs[r];
#pragma unroll
    for (int g = 0; g < 4; ++g)
#pragma unroll
      for (int r = 0; r < 4; ++r)
        acc[g][r] *= fs[r];

    // P -> per-wave LDS (padded stride, no barrier needed)
#pragma unroll
    for (int ng = 0; ng < 4; ++ng)
#pragma unroll
      for (int r = 0; r < 4; ++r)
        myp[(lk * 4 + r) * PST + ng * 16 + lr] = f2bf(sc[ng][r]);
    bf16x8 pf[2];
#pragma unroll
    for (int kg = 0; kg < 2; ++kg)
      pf[kg] = *(const bf16x8*)&myp[lr * PST + kg * 32 + lk * 8];

    // PV
#pragma unroll
    for (int g = 0; g < 4; ++g)
#pragma unroll
      for (int kg = 0; kg < 2; ++kg)
        acc[g] = __builtin_amdgcn_mfma_f32_16x16x32_bf16(pf[kg], vf[g * 2 + kg], acc[g], 0, 0, 0);
  }

#pragma unroll
  for (int g = 0; g < 4; ++g)
#pragma unroll
    for (int r = 0; r < 4; ++r) {
      int q = q0 + lk * 4 + r;
      int d = g * 16 + lr;
      ctx[((size_t)b * S_ + q) * DM + h * AD + d] = f2bf(acc[g][r] / lrun[r]);
    }
}

extern "C" void kernel_launch(void* const* d_in, const int* in_sizes, int n_in,
                              void* d_out, int out_size, void* d_ws, size_t ws_size,
                              hipStream_t stream) {
  const float* states = (const float*)d_in[0];
  const float* Wq = (const float*)d_in[1];
  const float* bq = (const float*)d_in[2];
  const float* Wk = (const float*)d_in[3];
  const float* bk = (const float*)d_in[4];
  const float* Wv = (const float*)d_in[5];
  const float* bv = (const float*)d_in[6];
  const float* Wo = (const float*)d_in[7];
  const float* bo = (const float*)d_in[8];
  float* out = (float*)d_out;

  // workspace layout (bf16 elems): states | Wt[4] | Q | K | Vt | ctx
  u16* sbf = (u16*)d_ws;
  u16* wt  = sbf + ME;
  u16* Qw  = wt + ME;
  u16* Kw  = Qw + ME;
  u16* Vtw = Kw + ME;
  u16* ctx = Vtw + ME;

  conv_states<<<ME / (256 * 8), 256, 0, stream>>>(states, sbf);
  transpose_w<<<dim3(32, 32, 4), dim3(32, 32), 0, stream>>>(Wq, Wk, Wv, Wo, wt);
  qkv_gemm<<<dim3(8, 32, 3), 256, 0, stream>>>(sbf, wt, bq, bk, bv, Qw, Kw, Vtw);
  attn_kernel<<<dim3(32, 32), 256, 0, stream>>>(Qw, Kw, Vtw, ctx);
  out_gemm<<<dim3(8, 32), 256, 0, stream>>>(ctx, wt + 3 * (size_t)DM * DM, bo, out);
}

// Round 3
// 149.445 us; speedup vs baseline: 2.6888x; 2.2619x over previous
//
#include <hip/hip_runtime.h>
#include <math.h>

typedef unsigned short u16;
typedef __attribute__((ext_vector_type(4))) float f32x4;
typedef __attribute__((ext_vector_type(16))) float f32x16;
typedef __attribute__((ext_vector_type(8))) short bf16x8;

#define B_ 2
#define S_ 2048
#define DM 1024
#define H_ 16
#define AD 64
#define ME 4194304  // elems in one 4096x1024 matrix
#define SC 0.18033688011112042f  // 0.125 * log2(e)

#define GLL(g, s) __builtin_amdgcn_global_load_lds( \
  (const __attribute__((address_space(1))) void*)(g), \
  (__attribute__((address_space(3))) void*)(s), 16, 0, 0)

__device__ inline u16 f2bf(float f) {
  union { float f; unsigned u; } v; v.f = f;
  unsigned r = v.u + 0x7fffu + ((v.u >> 16) & 1u);
  return (u16)(r >> 16);
}

__device__ inline unsigned cvt_pk_bf16(float lo, float hi) {
  unsigned r;
  asm("v_cvt_pk_bf16_f32 %0, %1, %2" : "=v"(r) : "v"(lo), "v"(hi));
  return r;
}

// ---------------- states f32 -> bf16 ----------------
__global__ __launch_bounds__(256) void conv_states(const float* __restrict__ in,
                                                   u16* __restrict__ out) {
  int i = (blockIdx.x * 256 + threadIdx.x) * 8;
  const float4* p = (const float4*)(in + i);
  float4 a = p[0], b = p[1];
  bf16x8 o;
  o[0] = (short)f2bf(a.x); o[1] = (short)f2bf(a.y);
  o[2] = (short)f2bf(a.z); o[3] = (short)f2bf(a.w);
  o[4] = (short)f2bf(b.x); o[5] = (short)f2bf(b.y);
  o[6] = (short)f2bf(b.z); o[7] = (short)f2bf(b.w);
  *(bf16x8*)&out[i] = o;
}

// ---------------- W [K][N] f32 -> Wt [N][K] bf16 (4 weights) ----------------
__global__ void transpose_w(const float* __restrict__ Wq, const float* __restrict__ Wk,
                            const float* __restrict__ Wv, const float* __restrict__ Wo,
                            u16* __restrict__ Wt) {
  __shared__ float t[32][33];
  int z = blockIdx.z;
  const float* W = (z == 0) ? Wq : (z == 1) ? Wk : (z == 2) ? Wv : Wo;
  u16* out = Wt + (size_t)z * DM * DM;
  int n0 = blockIdx.x * 32, k0 = blockIdx.y * 32;
  int tx = threadIdx.x, ty = threadIdx.y;
  t[ty][tx] = W[(k0 + ty) * DM + n0 + tx];
  __syncthreads();
  out[(n0 + ty) * DM + k0 + tx] = f2bf(t[tx][ty]);
}

// ---------------- fused QKV projection GEMM + tanh ----------------
__global__ __launch_bounds__(256) void qkv_gemm(
    const u16* __restrict__ A, const u16* __restrict__ Wt,
    const float* __restrict__ bq, const float* __restrict__ bk, const float* __restrict__ bv,
    u16* __restrict__ Qw, u16* __restrict__ Kw, u16* __restrict__ Vtw) {
  __shared__ __attribute__((aligned(16))) u16 lA[128 * 32];
  __shared__ __attribute__((aligned(16))) u16 lB[128 * 32];
  const int z = blockIdx.z;
  const u16* Bt = Wt + (size_t)z * DM * DM;
  const int m0 = blockIdx.y * 128, n0 = blockIdx.x * 128;
  const int tid = threadIdx.x;
  const int wid = tid >> 6, l = tid & 63;
  const int lr = l & 15, lk = l >> 4;
  const int wm = (wid >> 1) * 64, wn = (wid & 1) * 64;
  const int srow = wid * 32 + (l >> 2);
  const int scol = (l & 3) * 8;

  f32x4 acc[4][4] = {};

  for (int k0 = 0; k0 < DM; k0 += 32) {
    const u16* gA = &A[(size_t)(m0 + srow) * DM + k0 + scol];
    const u16* gB = &Bt[(size_t)(n0 + srow) * DM + k0 + scol];
    GLL(gA,           lA + wid * 1024);
    GLL(gA + 16 * DM, lA + wid * 1024 + 512);
    GLL(gB,           lB + wid * 1024);
    GLL(gB + 16 * DM, lB + wid * 1024 + 512);
    __syncthreads();
    bf16x8 af[4], bfr[4];
#pragma unroll
    for (int g = 0; g < 4; ++g) {
      af[g]  = *(const bf16x8*)&lA[(wm + g * 16 + lr) * 32 + lk * 8];
      bfr[g] = *(const bf16x8*)&lB[(wn + g * 16 + lr) * 32 + lk * 8];
    }
#pragma unroll
    for (int mg = 0; mg < 4; ++mg)
#pragma unroll
      for (int ng = 0; ng < 4; ++ng)
        acc[mg][ng] = __builtin_amdgcn_mfma_f32_16x16x32_bf16(af[mg], bfr[ng], acc[mg][ng], 0, 0, 0);
    __syncthreads();
  }

  const float* bias = (z == 0) ? bq : (z == 1) ? bk : bv;
#pragma unroll
  for (int mg = 0; mg < 4; ++mg)
#pragma unroll
    for (int ng = 0; ng < 4; ++ng)
#pragma unroll
      for (int r = 0; r < 4; ++r) {
        int m = m0 + wm + mg * 16 + lk * 4 + r;
        int n = n0 + wn + ng * 16 + lr;
        float v = tanhf(acc[mg][ng][r] + bias[n]);
        u16 h16 = f2bf(v);
        int bb = m >> 11, s = m & 2047, hh = n >> 6, d = n & 63;
        if (z == 2) Vtw[((size_t)(bb * H_ + hh) * AD + d) * S_ + s] = h16;
        else ((z == 0) ? Qw : Kw)[((size_t)(bb * H_ + hh) * S_ + s) * AD + d] = h16;
      }
}

// ---------------- output projection GEMM + tanh (f32 out) ----------------
__global__ __launch_bounds__(256) void out_gemm(
    const u16* __restrict__ A, const u16* __restrict__ Bt,
    const float* __restrict__ bo, float* __restrict__ out) {
  __shared__ __attribute__((aligned(16))) u16 lA[128 * 32];
  __shared__ __attribute__((aligned(16))) u16 lB[128 * 32];
  const int m0 = blockIdx.y * 128, n0 = blockIdx.x * 128;
  const int tid = threadIdx.x;
  const int wid = tid >> 6, l = tid & 63;
  const int lr = l & 15, lk = l >> 4;
  const int wm = (wid >> 1) * 64, wn = (wid & 1) * 64;
  const int srow = wid * 32 + (l >> 2);
  const int scol = (l & 3) * 8;

  f32x4 acc[4][4] = {};

  for (int k0 = 0; k0 < DM; k0 += 32) {
    const u16* gA = &A[(size_t)(m0 + srow) * DM + k0 + scol];
    const u16* gB = &Bt[(size_t)(n0 + srow) * DM + k0 + scol];
    GLL(gA,           lA + wid * 1024);
    GLL(gA + 16 * DM, lA + wid * 1024 + 512);
    GLL(gB,           lB + wid * 1024);
    GLL(gB + 16 * DM, lB + wid * 1024 + 512);
    __syncthreads();
    bf16x8 af[4], bfr[4];
#pragma unroll
    for (int g = 0; g < 4; ++g) {
      af[g]  = *(const bf16x8*)&lA[(wm + g * 16 + lr) * 32 + lk * 8];
      bfr[g] = *(const bf16x8*)&lB[(wn + g * 16 + lr) * 32 + lk * 8];
    }
#pragma unroll
    for (int mg = 0; mg < 4; ++mg)
#pragma unroll
      for (int ng = 0; ng < 4; ++ng)
        acc[mg][ng] = __builtin_amdgcn_mfma_f32_16x16x32_bf16(af[mg], bfr[ng], acc[mg][ng], 0, 0, 0);
    __syncthreads();
  }

#pragma unroll
  for (int mg = 0; mg < 4; ++mg)
#pragma unroll
    for (int ng = 0; ng < 4; ++ng)
#pragma unroll
      for (int r = 0; r < 4; ++r) {
        int m = m0 + wm + mg * 16 + lk * 4 + r;
        int n = n0 + wn + ng * 16 + lr;
        out[(size_t)m * DM + n] = tanhf(acc[mg][ng][r] + bo[n]);
      }
}

// ---------------- causal flash attention (swapped-operand, 32x32 MFMA) ------
// Q,K: [B][H][S][64] bf16; Vt: [B][H][64][S] bf16; ctx: [B][S][H*64] bf16.
// Block = 512 thr (8 waves). Waves 0-3 own q-tile p, waves 4-7 own tile 15-p
// (128 rows each, 32 rows/wave). KVBLK=128 double-buffered in LDS, shared by
// all 8 waves. Per block: exactly 17 compute iters (perfect balance).
// LDS: K packed [64][256B] (2 kv-rows per LDS row), V^T [64][256B]; both
// XOR-swizzled (byte ^= (row&15)<<4) via pre-swizzled global_load_lds source.
__global__ __launch_bounds__(512, 2) void attn_kernel(
    const u16* __restrict__ Q, const u16* __restrict__ K,
    const u16* __restrict__ Vt, u16* __restrict__ ctx) {
  __shared__ __attribute__((aligned(16))) char smem[65536];
  const int p = blockIdx.x;          // pair id 0..7
  const int bh = blockIdx.y;
  const int b = bh >> 4, h = bh & 15;
  const int tid = threadIdx.x, wid = tid >> 6, l = tid & 63;
  const int lq = l & 31, hi = l >> 5;
  const int grp = wid >> 2, wl = wid & 3;
  const int tmy = grp ? (15 - p) : p;  // this wave-group's q-tile
  const int nkb = 16 - p;              // staged kv-blocks (max over pair)
  const int q0 = tmy * 128 + wl * 32;  // wave's first q row

  const char* Qb = (const char*)(Q + (size_t)bh * S_ * AD);
  const char* Kb = (const char*)(K + (size_t)bh * S_ * AD);
  const char* Vb = (const char*)(Vt + (size_t)bh * AD * S_);

  // staging lane constants: each wave stages 2x1KB of K and 2x1KB of V
  int kcst[2], vcst[2], ldso[2];
#pragma unroll
  for (int i = 0; i < 2; ++i) {
    int o = wid * 2048 + i * 1024 + l * 16;   // linear dest byte in 16KB tile
    ldso[i] = wid * 2048 + i * 1024;          // wave-uniform dest base
    int row = o >> 8;                         // K: packed row-pair; V: d row
    int inrow = o & 255;
    int un = inrow ^ ((row & 15) << 4);       // inverse swizzle (involution)
    kcst[i] = (row * 2 + (un >> 7)) * 128 + (un & 127);
    vcst[i] = row * (2 * S_) + un;
  }

  // Q fragments: lane holds Q[q0+lq][ds*16 + hi*8 .. +7] for ds=0..3
  bf16x8 qf[4];
#pragma unroll
  for (int ds = 0; ds < 4; ++ds)
    qf[ds] = *(const bf16x8*)(Qb + (size_t)(q0 + lq) * 128 + ds * 32 + hi * 16);

  f32x16 accO[2] = {};
  float mrun = -3e38f, lrun = 0.f;

  // prologue: stage kv-block 0 into buf 0
#pragma unroll
  for (int i = 0; i < 2; ++i) {
    GLL(Kb + kcst[i], smem + ldso[i]);
    GLL(Vb + vcst[i], smem + 32768 + ldso[i]);
  }
  asm volatile("s_waitcnt vmcnt(0)" ::: "memory");
  __syncthreads();

  for (int kb = 0; kb < nkb; ++kb) {
    const int buf = kb & 1;
    if (kb + 1 < nkb) {
      const int nb = kb + 1, nbuf = buf ^ 1;
#pragma unroll
      for (int i = 0; i < 2; ++i) {
        GLL(Kb + nb * 16384 + kcst[i], smem + nbuf * 16384 + ldso[i]);
        GLL(Vb + nb * 256  + vcst[i], smem + 32768 + nbuf * 16384 + ldso[i]);
      }
    }

    if (kb <= tmy) {
      const char* kl = smem + buf * 16384;
      const char* vl = smem + 32768 + buf * 16384;
      const bool diag = (kb == tmy);
      const int wlim = diag ? wl : 3;

      // QK^T (swapped): cs[s][r] = S^T[kv = s*32 + crow(r,hi)][q = lq]
      f32x16 cs[4];
#pragma unroll
      for (int s = 0; s < 4; ++s) {
        if (s > wlim) continue;
        f32x16 c = {};
        const int kvl = s * 32 + lq;
        const int rp = kvl >> 1, kbit = kvl & 1;
        const int swz = (rp & 15) << 4;
#pragma unroll
        for (int ds = 0; ds < 4; ++ds) {
          bf16x8 a = *(const bf16x8*)(kl + rp * 256 +
                       (((kbit << 7) | (ds * 32 + hi * 16)) ^ swz));
          c = __builtin_amdgcn_mfma_f32_32x32x16_bf16(a, qf[ds], c, 0, 0, 0);
        }
        cs[s] = c;
      }

      // scale + causal mask + row max (in-lane + 1 shfl)
      float mloc = -3e38f;
#pragma unroll
      for (int s = 0; s < 4; ++s) {
        if (s > wlim) continue;
        const bool tri = diag && (s == wl);
#pragma unroll
        for (int r = 0; r < 16; ++r) {
          float v = cs[s][r] * SC;
          if (tri) {
            int kvl = (r & 3) + 8 * (r >> 2) + 4 * hi;
            if (kvl > lq) v = -3e38f;
          }
          cs[s][r] = v;
          mloc = fmaxf(mloc, v);
        }
      }
      mloc = fmaxf(mloc, __shfl_xor(mloc, 32));
      float mnew = fmaxf(mrun, mloc);
      float alpha = exp2f(mrun - mnew);
      mrun = mnew;

      float rsum = 0.f;
#pragma unroll
      for (int s = 0; s < 4; ++s) {
        if (s > wlim) continue;
#pragma unroll
        for (int r = 0; r < 16; ++r) {
          float e = exp2f(cs[s][r] - mnew);
          cs[s][r] = e;
          rsum += e;
        }
      }
      rsum += __shfl_xor(rsum, 32);
      lrun = lrun * alpha + rsum;
#pragma unroll
      for (int d = 0; d < 2; ++d)
#pragma unroll
        for (int r = 0; r < 16; ++r) accO[d][r] *= alpha;

      // P -> bf16 B-frags (pack + half-swap) and PV: O^T += V^T * P^T
#pragma unroll
      for (int s = 0; s < 4; ++s) {
        if (s > wlim) continue;
        unsigned u[8], su[8];
#pragma unroll
        for (int i = 0; i < 8; ++i) {
          u[i]  = cvt_pk_bf16(cs[s][2 * i], cs[s][2 * i + 1]);
          su[i] = (unsigned)__shfl_xor((int)u[i], 32);
        }
        union { unsigned w[4]; bf16x8 v; } c0, c1;
        c0.w[0] = hi ? su[2] : u[0];  c0.w[1] = hi ? su[3] : u[1];
        c0.w[2] = hi ? u[2]  : su[0]; c0.w[3] = hi ? u[3]  : su[1];
        c1.w[0] = hi ? su[6] : u[4];  c1.w[1] = hi ? su[7] : u[5];
        c1.w[2] = hi ? u[6]  : su[4]; c1.w[3] = hi ? u[7]  : su[5];
#pragma unroll
        for (int d = 0; d < 2; ++d) {
          const int drow = d * 32 + lq;
          const int vswz = (drow & 15) << 4;
          bf16x8 a0 = *(const bf16x8*)(vl + drow * 256 + ((s * 64 + hi * 16) ^ vswz));
          bf16x8 a1 = *(const bf16x8*)(vl + drow * 256 + ((s * 64 + 32 + hi * 16) ^ vswz));
          accO[d] = __builtin_amdgcn_mfma_f32_32x32x16_bf16(a0, c0.v, accO[d], 0, 0, 0);
          accO[d] = __builtin_amdgcn_mfma_f32_32x32x16_bf16(a1, c1.v, accO[d], 0, 0, 0);
        }
      }
    }

    asm volatile("s_waitcnt vmcnt(0)" ::: "memory");
    __syncthreads();
  }

  // epilogue: lane owns q = q0+lq; O^T regs: d = dblk*32 + (r&3)+8*(r>>2)+4*hi
  const float inv = 1.f / lrun;
  u16* cb_ = ctx + ((size_t)b * S_ + (q0 + lq)) * DM + h * AD;
#pragma unroll
  for (int d = 0; d < 2; ++d)
#pragma unroll
    for (int g = 0; g < 4; ++g) {
      unsigned w0 = cvt_pk_bf16(accO[d][4 * g] * inv,     accO[d][4 * g + 1] * inv);
      unsigned w1 = cvt_pk_bf16(accO[d][4 * g + 2] * inv, accO[d][4 * g + 3] * inv);
      unsigned* dst = (unsigned*)(cb_ + d * 32 + 8 * g + 4 * hi);
      dst[0] = w0; dst[1] = w1;
    }
}

extern "C" void kernel_launch(void* const* d_in, const int* in_sizes, int n_in,
                              void* d_out, int out_size, void* d_ws, size_t ws_size,
                              hipStream_t stream) {
  const float* states = (const float*)d_in[0];
  const float* Wq = (const float*)d_in[1];
  const float* bq = (const float*)d_in[2];
  const float* Wk = (const float*)d_in[3];
  const float* bk = (const float*)d_in[4];
  const float* Wv = (const float*)d_in[5];
  const float* bv = (const float*)d_in[6];
  const float* Wo = (const float*)d_in[7];
  const float* bo = (const float*)d_in[8];
  float* out = (float*)d_out;

  u16* sbf = (u16*)d_ws;
  u16* wt  = sbf + ME;
  u16* Qw  = wt + ME;
  u16* Kw  = Qw + ME;
  u16* Vtw = Kw + ME;
  u16* ctx = Vtw + ME;

  conv_states<<<ME / (256 * 8), 256, 0, stream>>>(states, sbf);
  transpose_w<<<dim3(32, 32, 4), dim3(32, 32), 0, stream>>>(Wq, Wk, Wv, Wo, wt);
  qkv_gemm<<<dim3(8, 32, 3), 256, 0, stream>>>(sbf, wt, bq, bk, bv, Qw, Kw, Vtw);
  attn_kernel<<<dim3(8, 32), 512, 0, stream>>>(Qw, Kw, Vtw, ctx);
  out_gemm<<<dim3(8, 32), 256, 0, stream>>>(ctx, wt + 3 * (size_t)DM * DM, bo, out);
}

// Round 4
// 136.016 us; speedup vs baseline: 2.9543x; 1.0987x over previous
//
#include <hip/hip_runtime.h>
#include <math.h>

typedef unsigned short u16;
typedef __attribute__((ext_vector_type(4))) float f32x4;
typedef __attribute__((ext_vector_type(16))) float f32x16;
typedef __attribute__((ext_vector_type(8))) short bf16x8;

#define B_ 2
#define S_ 2048
#define DM 1024
#define H_ 16
#define AD 64
#define ME 4194304  // elems in one 4096x1024 matrix
#define SC 0.18033688011112042f  // 0.125 * log2(e), folded into Q
#define SMAX 12.0f               // static softmax max: |logit*log2e| <= 11.54

#define GLL(g, s) __builtin_amdgcn_global_load_lds( \
  (const __attribute__((address_space(1))) void*)(g), \
  (__attribute__((address_space(3))) void*)(s), 16, 0, 0)

__device__ inline u16 f2bf(float f) {
  union { float f; unsigned u; } v; v.f = f;
  unsigned r = v.u + 0x7fffu + ((v.u >> 16) & 1u);
  return (u16)(r >> 16);
}

__device__ inline unsigned cvt_pk_bf16(float lo, float hi) {
  unsigned r;
  asm("v_cvt_pk_bf16_f32 %0, %1, %2" : "=v"(r) : "v"(lo), "v"(hi));
  return r;
}

// ---------------- states f32 -> bf16 ----------------
__global__ __launch_bounds__(256) void conv_states(const float* __restrict__ in,
                                                   u16* __restrict__ out) {
  int i = (blockIdx.x * 256 + threadIdx.x) * 8;
  const float4* p = (const float4*)(in + i);
  float4 a = p[0], b = p[1];
  bf16x8 o;
  o[0] = (short)f2bf(a.x); o[1] = (short)f2bf(a.y);
  o[2] = (short)f2bf(a.z); o[3] = (short)f2bf(a.w);
  o[4] = (short)f2bf(b.x); o[5] = (short)f2bf(b.y);
  o[6] = (short)f2bf(b.z); o[7] = (short)f2bf(b.w);
  *(bf16x8*)&out[i] = o;
}

// ---------------- W [K][N] f32 -> Wt [N][K] bf16 (4 weights) ----------------
__global__ void transpose_w(const float* __restrict__ Wq, const float* __restrict__ Wk,
                            const float* __restrict__ Wv, const float* __restrict__ Wo,
                            u16* __restrict__ Wt) {
  __shared__ float t[32][33];
  int z = blockIdx.z;
  const float* W = (z == 0) ? Wq : (z == 1) ? Wk : (z == 2) ? Wv : Wo;
  u16* out = Wt + (size_t)z * DM * DM;
  int n0 = blockIdx.x * 32, k0 = blockIdx.y * 32;
  int tx = threadIdx.x, ty = threadIdx.y;
  t[ty][tx] = W[(k0 + ty) * DM + n0 + tx];
  __syncthreads();
  out[(n0 + ty) * DM + k0 + tx] = f2bf(t[tx][ty]);
}

// ---------------- fused QKV projection GEMM + tanh ----------------
__global__ __launch_bounds__(256) void qkv_gemm(
    const u16* __restrict__ A, const u16* __restrict__ Wt,
    const float* __restrict__ bq, const float* __restrict__ bk, const float* __restrict__ bv,
    u16* __restrict__ Qw, u16* __restrict__ Kw, u16* __restrict__ Vtw) {
  __shared__ __attribute__((aligned(16))) u16 lA[128 * 32];
  __shared__ __attribute__((aligned(16))) u16 lB[128 * 32];
  const int z = blockIdx.z;
  const u16* Bt = Wt + (size_t)z * DM * DM;
  const int m0 = blockIdx.y * 128, n0 = blockIdx.x * 128;
  const int tid = threadIdx.x;
  const int wid = tid >> 6, l = tid & 63;
  const int lr = l & 15, lk = l >> 4;
  const int wm = (wid >> 1) * 64, wn = (wid & 1) * 64;
  const int srow = wid * 32 + (l >> 2);
  const int scol = (l & 3) * 8;

  f32x4 acc[4][4] = {};

  for (int k0 = 0; k0 < DM; k0 += 32) {
    const u16* gA = &A[(size_t)(m0 + srow) * DM + k0 + scol];
    const u16* gB = &Bt[(size_t)(n0 + srow) * DM + k0 + scol];
    GLL(gA,           lA + wid * 1024);
    GLL(gA + 16 * DM, lA + wid * 1024 + 512);
    GLL(gB,           lB + wid * 1024);
    GLL(gB + 16 * DM, lB + wid * 1024 + 512);
    __syncthreads();
    bf16x8 af[4], bfr[4];
#pragma unroll
    for (int g = 0; g < 4; ++g) {
      af[g]  = *(const bf16x8*)&lA[(wm + g * 16 + lr) * 32 + lk * 8];
      bfr[g] = *(const bf16x8*)&lB[(wn + g * 16 + lr) * 32 + lk * 8];
    }
#pragma unroll
    for (int mg = 0; mg < 4; ++mg)
#pragma unroll
      for (int ng = 0; ng < 4; ++ng)
        acc[mg][ng] = __builtin_amdgcn_mfma_f32_16x16x32_bf16(af[mg], bfr[ng], acc[mg][ng], 0, 0, 0);
    __syncthreads();
  }

  const float* bias = (z == 0) ? bq : (z == 1) ? bk : bv;
#pragma unroll
  for (int mg = 0; mg < 4; ++mg)
#pragma unroll
    for (int ng = 0; ng < 4; ++ng)
#pragma unroll
      for (int r = 0; r < 4; ++r) {
        int m = m0 + wm + mg * 16 + lk * 4 + r;
        int n = n0 + wn + ng * 16 + lr;
        float v = tanhf(acc[mg][ng][r] + bias[n]);
        if (z == 0) v *= SC;  // fold softmax scale into Q
        u16 h16 = f2bf(v);
        int bb = m >> 11, s = m & 2047, hh = n >> 6, d = n & 63;
        if (z == 2) Vtw[((size_t)(bb * H_ + hh) * AD + d) * S_ + s] = h16;
        else ((z == 0) ? Qw : Kw)[((size_t)(bb * H_ + hh) * S_ + s) * AD + d] = h16;
      }
}

// ---------------- output projection GEMM + tanh (f32 out) ----------------
__global__ __launch_bounds__(256) void out_gemm(
    const u16* __restrict__ A, const u16* __restrict__ Bt,
    const float* __restrict__ bo, float* __restrict__ out) {
  __shared__ __attribute__((aligned(16))) u16 lA[128 * 32];
  __shared__ __attribute__((aligned(16))) u16 lB[128 * 32];
  const int m0 = blockIdx.y * 128, n0 = blockIdx.x * 128;
  const int tid = threadIdx.x;
  const int wid = tid >> 6, l = tid & 63;
  const int lr = l & 15, lk = l >> 4;
  const int wm = (wid >> 1) * 64, wn = (wid & 1) * 64;
  const int srow = wid * 32 + (l >> 2);
  const int scol = (l & 3) * 8;

  f32x4 acc[4][4] = {};

  for (int k0 = 0; k0 < DM; k0 += 32) {
    const u16* gA = &A[(size_t)(m0 + srow) * DM + k0 + scol];
    const u16* gB = &Bt[(size_t)(n0 + srow) * DM + k0 + scol];
    GLL(gA,           lA + wid * 1024);
    GLL(gA + 16 * DM, lA + wid * 1024 + 512);
    GLL(gB,           lB + wid * 1024);
    GLL(gB + 16 * DM, lB + wid * 1024 + 512);
    __syncthreads();
    bf16x8 af[4], bfr[4];
#pragma unroll
    for (int g = 0; g < 4; ++g) {
      af[g]  = *(const bf16x8*)&lA[(wm + g * 16 + lr) * 32 + lk * 8];
      bfr[g] = *(const bf16x8*)&lB[(wn + g * 16 + lr) * 32 + lk * 8];
    }
#pragma unroll
    for (int mg = 0; mg < 4; ++mg)
#pragma unroll
      for (int ng = 0; ng < 4; ++ng)
        acc[mg][ng] = __builtin_amdgcn_mfma_f32_16x16x32_bf16(af[mg], bfr[ng], acc[mg][ng], 0, 0, 0);
    __syncthreads();
  }

#pragma unroll
  for (int mg = 0; mg < 4; ++mg)
#pragma unroll
    for (int ng = 0; ng < 4; ++ng)
#pragma unroll
      for (int r = 0; r < 4; ++r) {
        int m = m0 + wm + mg * 16 + lk * 4 + r;
        int n = n0 + wn + ng * 16 + lr;
        out[(size_t)m * DM + n] = tanhf(acc[mg][ng][r] + bo[n]);
      }
}

// ---------------- causal flash attention (swapped-operand, static-max) ------
// Q(pre-scaled by SC),K: [B][H][S][64] bf16; Vt: [B][H][64][S] bf16;
// ctx: [B][S][H*64] bf16. Block = 256 thr (4 waves), one 128-row q-tile;
// wave wl owns rows [tile*128 + wl*32, +32). KVBLK=128 double-buffered LDS
// (K 16KB + V 16KB per buf, XOR-swizzled via pre-swizzled global src).
// Static max SMAX (tanh-bounded logits) -> no online rescale; lsum per-lane,
// one shfl at the end. Grid 512 blocks (2/CU), longest tiles first.
__global__ __launch_bounds__(256, 2) void attn_kernel(
    const u16* __restrict__ Q, const u16* __restrict__ K,
    const u16* __restrict__ Vt, u16* __restrict__ ctx) {
  __shared__ __attribute__((aligned(16))) char smem[65536];
  const int bid = blockIdx.x;
  const int t = 15 - (bid >> 5);     // q-tile; longest first
  const int bh = bid & 31;
  const int b = bh >> 4, h = bh & 15;
  const int tid = threadIdx.x, wl = tid >> 6, l = tid & 63;
  const int lq = l & 31, hi = l >> 5;
  const int q0 = t * 128 + wl * 32;

  const char* Qb = (const char*)(Q + (size_t)bh * S_ * AD);
  const char* Kb = (const char*)(K + (size_t)bh * S_ * AD);
  const char* Vb = (const char*)(Vt + (size_t)bh * AD * S_);

  // staging constants: 16 chunks of 1KB each for K and V; wave wl owns 4.
  int kcst[4], vcst[4], ldso[4];
#pragma unroll
  for (int i = 0; i < 4; ++i) {
    int c = wl * 4 + i;
    int o = c * 1024 + l * 16;
    ldso[i] = c * 1024;
    int row = o >> 8;
    int un = (o & 255) ^ ((row & 15) << 4);
    kcst[i] = (row * 2 + (un >> 7)) * 128 + (un & 127);
    vcst[i] = row * (2 * S_) + un;
  }

  bf16x8 qf[4];
#pragma unroll
  for (int ds = 0; ds < 4; ++ds)
    qf[ds] = *(const bf16x8*)(Qb + (size_t)(q0 + lq) * 128 + ds * 32 + hi * 16);

  f32x16 accO[2] = {};
  float lsum = 0.f;

  // prologue: stage kv-block 0 into buf 0
#pragma unroll
  for (int i = 0; i < 4; ++i) {
    GLL(Kb + kcst[i], smem + ldso[i]);
    GLL(Vb + vcst[i], smem + 32768 + ldso[i]);
  }
  asm volatile("s_waitcnt vmcnt(0)" ::: "memory");
  __syncthreads();

  for (int kb = 0; kb <= t; ++kb) {
    const int buf = kb & 1;
    if (kb < t) {
      const int nb = kb + 1, nbuf = buf ^ 1;
#pragma unroll
      for (int i = 0; i < 4; ++i) {
        GLL(Kb + nb * 16384 + kcst[i], smem + nbuf * 16384 + ldso[i]);
        GLL(Vb + nb * 256  + vcst[i], smem + 32768 + nbuf * 16384 + ldso[i]);
      }
    }

    const char* kl = smem + buf * 16384;
    const char* vl = smem + 32768 + buf * 16384;
    const bool diag = (kb == t);
    const int wlim = diag ? wl : 3;

    for (int s = 0; s <= wlim; ++s) {
      // QK^T (swapped): c[r] = S^T[kv = s*32 + crow(r,hi)][q = lq] (log2 units)
      f32x16 c = {};
      const int kvl = s * 32 + lq;
      const int rp = kvl >> 1, kbit = kvl & 1;
      const int swz = (rp & 15) << 4;
      __builtin_amdgcn_s_setprio(1);
#pragma unroll
      for (int ds = 0; ds < 4; ++ds) {
        bf16x8 a = *(const bf16x8*)(kl + rp * 256 +
                     (((kbit << 7) | (ds * 32 + hi * 16)) ^ swz));
        c = __builtin_amdgcn_mfma_f32_32x32x16_bf16(a, qf[ds], c, 0, 0, 0);
      }
      __builtin_amdgcn_s_setprio(0);

      // p = exp2(s_hat - SMAX); causal zero on diagonal sub-block
      const bool tri = diag && (s == wl);
#pragma unroll
      for (int r = 0; r < 16; ++r) {
        float e = __builtin_amdgcn_exp2f(c[r] - SMAX);
        if (tri) {
          int kc = (r & 3) + 8 * (r >> 2) + 4 * hi;
          if (kc > lq) e = 0.f;
        }
        c[r] = e;
        lsum += e;
      }

      // pack to bf16 B-frags (cvt_pk + half-swap)
      unsigned u[8], su[8];
#pragma unroll
      for (int i = 0; i < 8; ++i) {
        u[i]  = cvt_pk_bf16(c[2 * i], c[2 * i + 1]);
        su[i] = (unsigned)__shfl_xor((int)u[i], 32);
      }
      union { unsigned w[4]; bf16x8 v; } c0, c1;
      c0.w[0] = hi ? su[2] : u[0];  c0.w[1] = hi ? su[3] : u[1];
      c0.w[2] = hi ? u[2]  : su[0]; c0.w[3] = hi ? u[3]  : su[1];
      c1.w[0] = hi ? su[6] : u[4];  c1.w[1] = hi ? su[7] : u[5];
      c1.w[2] = hi ? u[6]  : su[4]; c1.w[3] = hi ? u[7]  : su[5];

      // PV: O^T += V^T * P^T
      __builtin_amdgcn_s_setprio(1);
#pragma unroll
      for (int d = 0; d < 2; ++d) {
        const int drow = d * 32 + lq;
        const int vswz = (drow & 15) << 4;
        bf16x8 a0 = *(const bf16x8*)(vl + drow * 256 + ((s * 64 + hi * 16) ^ vswz));
        bf16x8 a1 = *(const bf16x8*)(vl + drow * 256 + ((s * 64 + 32 + hi * 16) ^ vswz));
        accO[d] = __builtin_amdgcn_mfma_f32_32x32x16_bf16(a0, c0.v, accO[d], 0, 0, 0);
        accO[d] = __builtin_amdgcn_mfma_f32_32x32x16_bf16(a1, c1.v, accO[d], 0, 0, 0);
      }
      __builtin_amdgcn_s_setprio(0);
    }

    asm volatile("s_waitcnt vmcnt(0)" ::: "memory");
    __syncthreads();
  }

  // epilogue: lane owns q = q0+lq; d = dblk*32 + (r&3)+8*(r>>2)+4*hi
  lsum += __shfl_xor(lsum, 32);
  const float inv = 1.f / lsum;
  u16* cb_ = ctx + ((size_t)b * S_ + (q0 + lq)) * DM + h * AD;
#pragma unroll
  for (int d = 0; d < 2; ++d)
#pragma unroll
    for (int g = 0; g < 4; ++g) {
      unsigned w0 = cvt_pk_bf16(accO[d][4 * g] * inv,     accO[d][4 * g + 1] * inv);
      unsigned w1 = cvt_pk_bf16(accO[d][4 * g + 2] * inv, accO[d][4 * g + 3] * inv);
      unsigned* dst = (unsigned*)(cb_ + d * 32 + 8 * g + 4 * hi);
      dst[0] = w0; dst[1] = w1;
    }
}

extern "C" void kernel_launch(void* const* d_in, const int* in_sizes, int n_in,
                              void* d_out, int out_size, void* d_ws, size_t ws_size,
                              hipStream_t stream) {
  const float* states = (const float*)d_in[0];
  const float* Wq = (const float*)d_in[1];
  const float* bq = (const float*)d_in[2];
  const float* Wk = (const float*)d_in[3];
  const float* bk = (const float*)d_in[4];
  const float* Wv = (const float*)d_in[5];
  const float* bv = (const float*)d_in[6];
  const float* Wo = (const float*)d_in[7];
  const float* bo = (const float*)d_in[8];
  float* out = (float*)d_out;

  u16* sbf = (u16*)d_ws;
  u16* wt  = sbf + ME;
  u16* Qw  = wt + ME;
  u16* Kw  = Qw + ME;
  u16* Vtw = Kw + ME;
  u16* ctx = Vtw + ME;

  conv_states<<<ME / (256 * 8), 256, 0, stream>>>(states, sbf);
  transpose_w<<<dim3(32, 32, 4), dim3(32, 32), 0, stream>>>(Wq, Wk, Wv, Wo, wt);
  qkv_gemm<<<dim3(8, 32, 3), 256, 0, stream>>>(sbf, wt, bq, bk, bv, Qw, Kw, Vtw);
  attn_kernel<<<512, 256, 0, stream>>>(Qw, Kw, Vtw, ctx);
  out_gemm<<<dim3(8, 32), 256, 0, stream>>>(ctx, wt + 3 * (size_t)DM * DM, bo, out);
}

// Round 5
// 132.391 us; speedup vs baseline: 3.0352x; 1.0274x over previous
//
#include <hip/hip_runtime.h>
#include <math.h>

typedef unsigned short u16;
typedef __attribute__((ext_vector_type(4))) float f32x4;
typedef __attribute__((ext_vector_type(16))) float f32x16;
typedef __attribute__((ext_vector_type(8))) short bf16x8;

#define B_ 2
#define S_ 2048
#define DM 1024
#define H_ 16
#define AD 64
#define ME 4194304  // elems in one 4096x1024 matrix
#define SC 0.18033688011112042f  // 0.125 * log2(e), folded into Q
#define SMAX 12.0f               // static softmax max: |logit*log2e| <= 11.54

#define GLL(g, s) __builtin_amdgcn_global_load_lds( \
  (const __attribute__((address_space(1))) void*)(g), \
  (__attribute__((address_space(3))) void*)(s), 16, 0, 0)

__device__ inline u16 f2bf(float f) {
  union { float f; unsigned u; } v; v.f = f;
  unsigned r = v.u + 0x7fffu + ((v.u >> 16) & 1u);
  return (u16)(r >> 16);
}

__device__ inline unsigned cvt_pk_bf16(float lo, float hi) {
  unsigned r;
  asm("v_cvt_pk_bf16_f32 %0, %1, %2" : "=v"(r) : "v"(lo), "v"(hi));
  return r;
}

// ---------------- states f32 -> bf16 ----------------
__global__ __launch_bounds__(256) void conv_states(const float* __restrict__ in,
                                                   u16* __restrict__ out) {
  int i = (blockIdx.x * 256 + threadIdx.x) * 8;
  const float4* p = (const float4*)(in + i);
  float4 a = p[0], b = p[1];
  bf16x8 o;
  o[0] = (short)f2bf(a.x); o[1] = (short)f2bf(a.y);
  o[2] = (short)f2bf(a.z); o[3] = (short)f2bf(a.w);
  o[4] = (short)f2bf(b.x); o[5] = (short)f2bf(b.y);
  o[6] = (short)f2bf(b.z); o[7] = (short)f2bf(b.w);
  *(bf16x8*)&out[i] = o;
}

// ---------------- W [K][N] f32 -> Wt [N][K] bf16 (4 weights) ----------------
__global__ void transpose_w(const float* __restrict__ Wq, const float* __restrict__ Wk,
                            const float* __restrict__ Wv, const float* __restrict__ Wo,
                            u16* __restrict__ Wt) {
  __shared__ float t[32][33];
  int z = blockIdx.z;
  const float* W = (z == 0) ? Wq : (z == 1) ? Wk : (z == 2) ? Wv : Wo;
  u16* out = Wt + (size_t)z * DM * DM;
  int n0 = blockIdx.x * 32, k0 = blockIdx.y * 32;
  int tx = threadIdx.x, ty = threadIdx.y;
  t[ty][tx] = W[(k0 + ty) * DM + n0 + tx];
  __syncthreads();
  out[(n0 + ty) * DM + k0 + tx] = f2bf(t[tx][ty]);
}

// ---------------- fused QKV projection GEMM + tanh ----------------
__global__ __launch_bounds__(256) void qkv_gemm(
    const u16* __restrict__ A, const u16* __restrict__ Wt,
    const float* __restrict__ bq, const float* __restrict__ bk, const float* __restrict__ bv,
    u16* __restrict__ Qw, u16* __restrict__ Kw, u16* __restrict__ Vtw) {
  __shared__ __attribute__((aligned(16))) u16 lA[128 * 32];
  __shared__ __attribute__((aligned(16))) u16 lB[128 * 32];
  const int z = blockIdx.z;
  const u16* Bt = Wt + (size_t)z * DM * DM;
  const int m0 = blockIdx.y * 128, n0 = blockIdx.x * 128;
  const int tid = threadIdx.x;
  const int wid = tid >> 6, l = tid & 63;
  const int lr = l & 15, lk = l >> 4;
  const int wm = (wid >> 1) * 64, wn = (wid & 1) * 64;
  const int srow = wid * 32 + (l >> 2);
  const int scol = (l & 3) * 8;

  f32x4 acc[4][4] = {};

  for (int k0 = 0; k0 < DM; k0 += 32) {
    const u16* gA = &A[(size_t)(m0 + srow) * DM + k0 + scol];
    const u16* gB = &Bt[(size_t)(n0 + srow) * DM + k0 + scol];
    GLL(gA,           lA + wid * 1024);
    GLL(gA + 16 * DM, lA + wid * 1024 + 512);
    GLL(gB,           lB + wid * 1024);
    GLL(gB + 16 * DM, lB + wid * 1024 + 512);
    __syncthreads();
    bf16x8 af[4], bfr[4];
#pragma unroll
    for (int g = 0; g < 4; ++g) {
      af[g]  = *(const bf16x8*)&lA[(wm + g * 16 + lr) * 32 + lk * 8];
      bfr[g] = *(const bf16x8*)&lB[(wn + g * 16 + lr) * 32 + lk * 8];
    }
#pragma unroll
    for (int mg = 0; mg < 4; ++mg)
#pragma unroll
      for (int ng = 0; ng < 4; ++ng)
        acc[mg][ng] = __builtin_amdgcn_mfma_f32_16x16x32_bf16(af[mg], bfr[ng], acc[mg][ng], 0, 0, 0);
    __syncthreads();
  }

  const float* bias = (z == 0) ? bq : (z == 1) ? bk : bv;
#pragma unroll
  for (int mg = 0; mg < 4; ++mg)
#pragma unroll
    for (int ng = 0; ng < 4; ++ng)
#pragma unroll
      for (int r = 0; r < 4; ++r) {
        int m = m0 + wm + mg * 16 + lk * 4 + r;
        int n = n0 + wn + ng * 16 + lr;
        float v = tanhf(acc[mg][ng][r] + bias[n]);
        if (z == 0) v *= SC;  // fold softmax scale into Q
        u16 h16 = f2bf(v);
        int bb = m >> 11, s = m & 2047, hh = n >> 6, d = n & 63;
        if (z == 2) Vtw[((size_t)(bb * H_ + hh) * AD + d) * S_ + s] = h16;
        else ((z == 0) ? Qw : Kw)[((size_t)(bb * H_ + hh) * S_ + s) * AD + d] = h16;
      }
}

// ---------------- output projection GEMM + tanh (f32 out) ----------------
__global__ __launch_bounds__(256) void out_gemm(
    const u16* __restrict__ A, const u16* __restrict__ Bt,
    const float* __restrict__ bo, float* __restrict__ out) {
  __shared__ __attribute__((aligned(16))) u16 lA[128 * 32];
  __shared__ __attribute__((aligned(16))) u16 lB[128 * 32];
  const int m0 = blockIdx.y * 128, n0 = blockIdx.x * 128;
  const int tid = threadIdx.x;
  const int wid = tid >> 6, l = tid & 63;
  const int lr = l & 15, lk = l >> 4;
  const int wm = (wid >> 1) * 64, wn = (wid & 1) * 64;
  const int srow = wid * 32 + (l >> 2);
  const int scol = (l & 3) * 8;

  f32x4 acc[4][4] = {};

  for (int k0 = 0; k0 < DM; k0 += 32) {
    const u16* gA = &A[(size_t)(m0 + srow) * DM + k0 + scol];
    const u16* gB = &Bt[(size_t)(n0 + srow) * DM + k0 + scol];
    GLL(gA,           lA + wid * 1024);
    GLL(gA + 16 * DM, lA + wid * 1024 + 512);
    GLL(gB,           lB + wid * 1024);
    GLL(gB + 16 * DM, lB + wid * 1024 + 512);
    __syncthreads();
    bf16x8 af[4], bfr[4];
#pragma unroll
    for (int g = 0; g < 4; ++g) {
      af[g]  = *(const bf16x8*)&lA[(wm + g * 16 + lr) * 32 + lk * 8];
      bfr[g] = *(const bf16x8*)&lB[(wn + g * 16 + lr) * 32 + lk * 8];
    }
#pragma unroll
    for (int mg = 0; mg < 4; ++mg)
#pragma unroll
      for (int ng = 0; ng < 4; ++ng)
        acc[mg][ng] = __builtin_amdgcn_mfma_f32_16x16x32_bf16(af[mg], bfr[ng], acc[mg][ng], 0, 0, 0);
    __syncthreads();
  }

#pragma unroll
  for (int mg = 0; mg < 4; ++mg)
#pragma unroll
    for (int ng = 0; ng < 4; ++ng)
#pragma unroll
      for (int r = 0; r < 4; ++r) {
        int m = m0 + wm + mg * 16 + lk * 4 + r;
        int n = n0 + wn + ng * 16 + lr;
        out[(size_t)m * DM + n] = tanhf(acc[mg][ng][r] + bo[n]);
      }
}

// ---------------- causal flash attention (split-KV, static-max) -------------
// Work unit u (0..23) per bh: tiles 0-7 = 1 chunk; tiles 8-15 = 2 chunks
// (kv 0-7 and kv 8-t). Chunks of <=8 kv-iters, dispatched big-first.
// Each chunk block writes f32 partial numerator O and denominator lsum;
// static max => partials combine by plain addition (attn_norm).
__global__ __launch_bounds__(256, 2) void attn_kernel(
    const u16* __restrict__ Q, const u16* __restrict__ K,
    const u16* __restrict__ Vt, float* __restrict__ O0, float* __restrict__ O1,
    float* __restrict__ L0, float* __restrict__ L1) {
  __shared__ __attribute__((aligned(16))) char smem[65536];
  const int u = blockIdx.x >> 5;
  const int bh = blockIdx.x & 31;
  int t, lo;
  if (u < 9)       { t = 7 + u; lo = 0; }
  else if (u == 9) { t = 15;    lo = 8; }
  else { int k = u - 10; int sz = 7 - (k >> 1);
         if (k & 1) { t = sz + 7; lo = 8; } else { t = sz - 1; lo = 0; } }
  const int khi = lo ? t : (t < 7 ? t : 7);

  const int tid = threadIdx.x, wl = tid >> 6, l = tid & 63;
  const int lq = l & 31, hl = l >> 5;
  const int q0 = t * 128 + wl * 32;

  const char* Qb = (const char*)(Q + (size_t)bh * S_ * AD);
  const char* Kb = (const char*)(K + (size_t)bh * S_ * AD);
  const char* Vb = (const char*)(Vt + (size_t)bh * AD * S_);

  // staging constants: 16 chunks of 1KB each for K and V; wave wl owns 4.
  int kcst[4], vcst[4], ldso[4];
#pragma unroll
  for (int i = 0; i < 4; ++i) {
    int c = wl * 4 + i;
    int o = c * 1024 + l * 16;
    ldso[i] = c * 1024;
    int row = o >> 8;
    int un = (o & 255) ^ ((row & 15) << 4);
    kcst[i] = (row * 2 + (un >> 7)) * 128 + (un & 127);
    vcst[i] = row * (2 * S_) + un;
  }

  bf16x8 qf[4];
#pragma unroll
  for (int ds = 0; ds < 4; ++ds)
    qf[ds] = *(const bf16x8*)(Qb + (size_t)(q0 + lq) * 128 + ds * 32 + hl * 16);

  f32x16 accO[2] = {};
  float lsum = 0.f;

  // prologue: stage kv-block `lo` into buf 0
#pragma unroll
  for (int i = 0; i < 4; ++i) {
    GLL(Kb + lo * 16384 + kcst[i], smem + ldso[i]);
    GLL(Vb + lo * 256  + vcst[i], smem + 32768 + ldso[i]);
  }
  asm volatile("s_waitcnt vmcnt(0)" ::: "memory");
  __syncthreads();

  for (int kb = lo; kb <= khi; ++kb) {
    const int buf = (kb - lo) & 1;
    if (kb < khi) {
      const int nb = kb + 1, nbuf = buf ^ 1;
#pragma unroll
      for (int i = 0; i < 4; ++i) {
        GLL(Kb + nb * 16384 + kcst[i], smem + nbuf * 16384 + ldso[i]);
        GLL(Vb + nb * 256  + vcst[i], smem + 32768 + nbuf * 16384 + ldso[i]);
      }
    }

    const char* kl = smem + buf * 16384;
    const char* vl = smem + 32768 + buf * 16384;
    const bool diag = (kb == t);
    const int wlim = diag ? wl : 3;

    for (int s = 0; s <= wlim; ++s) {
      // QK^T (swapped): c[r] = S^T[kv = s*32 + crow(r,hl)][q = lq] (log2 units)
      f32x16 c = {};
      const int kvl = s * 32 + lq;
      const int rp = kvl >> 1, kbit = kvl & 1;
      const int swz = (rp & 15) << 4;
      __builtin_amdgcn_s_setprio(1);
#pragma unroll
      for (int ds = 0; ds < 4; ++ds) {
        bf16x8 a = *(const bf16x8*)(kl + rp * 256 +
                     (((kbit << 7) | (ds * 32 + hl * 16)) ^ swz));
        c = __builtin_amdgcn_mfma_f32_32x32x16_bf16(a, qf[ds], c, 0, 0, 0);
      }
      __builtin_amdgcn_s_setprio(0);

      // p = exp2(s_hat - SMAX); causal zero on diagonal sub-block
      const bool tri = diag && (s == wl);
#pragma unroll
      for (int r = 0; r < 16; ++r) {
        float e = __builtin_amdgcn_exp2f(c[r] - SMAX);
        if (tri) {
          int kc = (r & 3) + 8 * (r >> 2) + 4 * hl;
          if (kc > lq) e = 0.f;
        }
        c[r] = e;
        lsum += e;
      }

      // pack to bf16 B-frags (cvt_pk + half-swap)
      unsigned uu[8], su[8];
#pragma unroll
      for (int i = 0; i < 8; ++i) {
        uu[i] = cvt_pk_bf16(c[2 * i], c[2 * i + 1]);
        su[i] = (unsigned)__shfl_xor((int)uu[i], 32);
      }
      union { unsigned w[4]; bf16x8 v; } c0, c1;
      c0.w[0] = hl ? su[2] : uu[0]; c0.w[1] = hl ? su[3] : uu[1];
      c0.w[2] = hl ? uu[2] : su[0]; c0.w[3] = hl ? uu[3] : su[1];
      c1.w[0] = hl ? su[6] : uu[4]; c1.w[1] = hl ? su[7] : uu[5];
      c1.w[2] = hl ? uu[6] : su[4]; c1.w[3] = hl ? uu[7] : su[5];

      // PV: O^T += V^T * P^T
      __builtin_amdgcn_s_setprio(1);
#pragma unroll
      for (int d = 0; d < 2; ++d) {
        const int drow = d * 32 + lq;
        const int vswz = (drow & 15) << 4;
        bf16x8 a0 = *(const bf16x8*)(vl + drow * 256 + ((s * 64 + hl * 16) ^ vswz));
        bf16x8 a1 = *(const bf16x8*)(vl + drow * 256 + ((s * 64 + 32 + hl * 16) ^ vswz));
        accO[d] = __builtin_amdgcn_mfma_f32_32x32x16_bf16(a0, c0.v, accO[d], 0, 0, 0);
        accO[d] = __builtin_amdgcn_mfma_f32_32x32x16_bf16(a1, c1.v, accO[d], 0, 0, 0);
      }
      __builtin_amdgcn_s_setprio(0);
    }

    asm volatile("s_waitcnt vmcnt(0)" ::: "memory");
    __syncthreads();
  }

  // epilogue: write f32 partials. lane owns q = q0+lq; d = db*32+8g+4hl+(0..3)
  lsum += __shfl_xor(lsum, 32);
  const int q = q0 + lq;
  float* Ob = lo ? O1 + ((size_t)bh * 1024 + (q - 1024)) * 64
                 : O0 + ((size_t)bh * 2048 + q) * 64;
#pragma unroll
  for (int d = 0; d < 2; ++d)
#pragma unroll
    for (int g = 0; g < 4; ++g) {
      f32x4 w;
      w[0] = accO[d][4 * g];     w[1] = accO[d][4 * g + 1];
      w[2] = accO[d][4 * g + 2]; w[3] = accO[d][4 * g + 3];
      *(f32x4*)&Ob[d * 32 + 8 * g + 4 * hl] = w;
    }
  if (!hl) {
    if (lo) L1[(size_t)bh * 1024 + (q - 1024)] = lsum;
    else    L0[(size_t)bh * 2048 + q] = lsum;
  }
}

// ---------------- combine partials, normalize, emit bf16 ctx ----------------
__global__ __launch_bounds__(256) void attn_norm(
    const float* __restrict__ O0, const float* __restrict__ O1,
    const float* __restrict__ L0, const float* __restrict__ L1,
    u16* __restrict__ ctx) {
  const int tid = threadIdx.x;
  const int row = blockIdx.x * 64 + (tid >> 2);  // bh*2048 + q
  const int sub = tid & 3;
  const int bh = row >> 11, q = row & 2047;
  float lv = L0[row];
  const f32x4* p0 = (const f32x4*)(O0 + (size_t)row * 64 + sub * 16);
  f32x4 v0 = p0[0], v1 = p0[1], v2 = p0[2], v3 = p0[3];
  if (q >= 1024) {
    size_t r1 = (size_t)bh * 1024 + (q - 1024);
    lv += L1[r1];
    const f32x4* p1 = (const f32x4*)(O1 + r1 * 64 + sub * 16);
    v0 += p1[0]; v1 += p1[1]; v2 += p1[2]; v3 += p1[3];
  }
  const float inv = 1.f / lv;
  const int b = bh >> 4, h = bh & 15;
  unsigned w[8];
  w[0] = cvt_pk_bf16(v0[0] * inv, v0[1] * inv);
  w[1] = cvt_pk_bf16(v0[2] * inv, v0[3] * inv);
  w[2] = cvt_pk_bf16(v1[0] * inv, v1[1] * inv);
  w[3] = cvt_pk_bf16(v1[2] * inv, v1[3] * inv);
  w[4] = cvt_pk_bf16(v2[0] * inv, v2[1] * inv);
  w[5] = cvt_pk_bf16(v2[2] * inv, v2[3] * inv);
  w[6] = cvt_pk_bf16(v3[0] * inv, v3[1] * inv);
  w[7] = cvt_pk_bf16(v3[2] * inv, v3[3] * inv);
  unsigned* dst = (unsigned*)(ctx + ((size_t)b * S_ + q) * DM + h * AD + sub * 16);
#pragma unroll
  for (int i = 0; i < 8; ++i) dst[i] = w[i];
}

extern "C" void kernel_launch(void* const* d_in, const int* in_sizes, int n_in,
                              void* d_out, int out_size, void* d_ws, size_t ws_size,
                              hipStream_t stream) {
  const float* states = (const float*)d_in[0];
  const float* Wq = (const float*)d_in[1];
  const float* bq = (const float*)d_in[2];
  const float* Wk = (const float*)d_in[3];
  const float* bk = (const float*)d_in[4];
  const float* Wv = (const float*)d_in[5];
  const float* bv = (const float*)d_in[6];
  const float* Wo = (const float*)d_in[7];
  const float* bo = (const float*)d_in[8];
  float* out = (float*)d_out;

  u16* sbf = (u16*)d_ws;
  u16* wt  = sbf + ME;
  u16* Qw  = wt + ME;
  u16* Kw  = Qw + ME;
  u16* Vtw = Kw + ME;
  u16* ctx = Vtw + ME;
  float* O0 = (float*)(ctx + ME);      // [32][2048][64] f32 partial numerators
  float* O1 = O0 + ME;                 // [32][1024][64] f32 (tiles 8-15 chunk 1)
  float* L0 = O1 + ME / 2;             // [32][2048] f32 partial denominators
  float* L1 = L0 + B_ * H_ * S_;       // [32][1024] f32

  conv_states<<<ME / (256 * 8), 256, 0, stream>>>(states, sbf);
  transpose_w<<<dim3(32, 32, 4), dim3(32, 32), 0, stream>>>(Wq, Wk, Wv, Wo, wt);
  qkv_gemm<<<dim3(8, 32, 3), 256, 0, stream>>>(sbf, wt, bq, bk, bv, Qw, Kw, Vtw);
  attn_kernel<<<768, 256, 0, stream>>>(Qw, Kw, Vtw, O0, O1, L0, L1);
  attn_norm<<<1024, 256, 0, stream>>>(O0, O1, L0, L1, ctx);
  out_gemm<<<dim3(8, 32), 256, 0, stream>>>(ctx, wt + 3 * (size_t)DM * DM, bo, out);
}